// Round 3
// baseline (265.249 us; speedup 1.0000x reference)
//
#include <hip/hip_runtime.h>
#include <hip/hip_bf16.h>

// B=2, IMG_DIM=VOXEL_DIM=QK_DIM=256, H=W=64, N=4096.
// Inputs/outputs are FP32 (reference dtype). Internal GEMMs use bf16 MFMA.

typedef __hip_bfloat16 bf16;
typedef __attribute__((ext_vector_type(8))) short bf16x8;   // 8 bf16 = 4 VGPRs
typedef __attribute__((ext_vector_type(4))) float f32x4;

__device__ __forceinline__ bf16x8 cvt8(const float* __restrict__ p) {
    // p is 16B-aligned (all call sites use 8-float-aligned offsets)
    const float4 a = *(const float4*)p;
    const float4 b = *(const float4*)(p + 4);
    bf16 t[8];
    t[0] = __float2bfloat16(a.x); t[1] = __float2bfloat16(a.y);
    t[2] = __float2bfloat16(a.z); t[3] = __float2bfloat16(a.w);
    t[4] = __float2bfloat16(b.x); t[5] = __float2bfloat16(b.y);
    t[6] = __float2bfloat16(b.z); t[7] = __float2bfloat16(b.w);
    return *(const bf16x8*)t;
}

// ---------------------------------------------------------------------------
// Kernel 1: projections.  blk = s*128 + b*64 + ntile
//   s=0: Q[q][o]  = img^T.Wq^T  -> Qw;   Vi[c'][p] = Wvi.img -> Vall[0:256)
//   s=1: Kt[p][o] = pc2^T.Wk^T  -> Ktw;  Vp[c'][p] = Wvp.pc2 -> Vall[256:512)
// X^T tile (64 pos x 256 cin) converted fp32->bf16 into LDS; weight fragments
// converted from global fp32 (L2-resident) per use.
// ---------------------------------------------------------------------------
__global__ __launch_bounds__(256) void proj_kernel(
    const float* __restrict__ img, const float* __restrict__ pc,
    const float* __restrict__ Wq,  const float* __restrict__ bq,
    const float* __restrict__ Wk,  const float* __restrict__ bk,
    const float* __restrict__ Wvi, const float* __restrict__ bvi,
    const float* __restrict__ Wvp, const float* __restrict__ bvp,
    bf16* __restrict__ Qw, bf16* __restrict__ Ktw, bf16* __restrict__ Vall)
{
    __shared__ __align__(16) bf16 XT[64][264];   // row = position, col = cin

    const int blk = blockIdx.x;
    const int s   = blk >> 7;
    const int b   = (blk >> 6) & 1;
    const int n0  = (blk & 63) * 64;
    const int tid = threadIdx.x;

    if (s == 0) {
        const float* src = img + b * 1048576;                 // [256][4096]
        for (int i = tid; i < 64 * 256; i += 256) {
            const int nl = i & 63, cin = i >> 6;
            XT[nl][cin] = __float2bfloat16(src[cin * 4096 + n0 + nl]);
        }
    } else {
        // pc[b][d][h][w][c]; pc2 channel ch=c*16+d; flat = d*65536 + n*16 + c
        const float* src = pc + b * 1048576;
        for (int i = tid; i < 64 * 256; i += 256) {
            const int nl = i & 63, ch = i >> 6;
            XT[nl][ch] = __float2bfloat16(src[(ch & 15) * 65536 + (n0 + nl) * 16 + (ch >> 4)]);
        }
    }
    __syncthreads();

    const float* W1 = s ? Wk  : Wq;   const float* B1 = s ? bk  : bq;
    const float* W2 = s ? Wvp : Wvi;  const float* B2 = s ? bvp : bvi;

    const int wv = tid >> 6, lane = tid & 63, l16 = lane & 15, quad = lane >> 4;
    const int ob = wv * 64;

    f32x4 acc1[4][4] = {};
    f32x4 acc2[4][4] = {};

    for (int ks = 0; ks < 8; ks++) {
        const int k0 = ks * 32;
        bf16x8 af[4], w1f[4], w2f[4];
        for (int ti = 0; ti < 4; ti++)
            af[ti] = *(const bf16x8*)&XT[ti * 16 + l16][k0 + quad * 8];
        for (int tj = 0; tj < 4; tj++) {
            const int o = ob + tj * 16 + l16;
            w1f[tj] = cvt8(&W1[o * 256 + k0 + quad * 8]);
            w2f[tj] = cvt8(&W2[o * 256 + k0 + quad * 8]);
        }
        for (int ti = 0; ti < 4; ti++)
            for (int tj = 0; tj < 4; tj++) {
                acc1[ti][tj] = __builtin_amdgcn_mfma_f32_16x16x32_bf16(af[ti], w1f[tj], acc1[ti][tj], 0, 0, 0);
                acc2[ti][tj] = __builtin_amdgcn_mfma_f32_16x16x32_bf16(af[ti], w2f[tj], acc2[ti][tj], 0, 0, 0);
            }
    }

    bf16* D1 = (s ? Ktw : Qw) + b * (4096 * 256);              // [n][o]
    bf16* D2 = Vall + b * (512 * 4096) + (s ? 256 * 4096 : 0); // [c'][p]

    for (int tj = 0; tj < 4; tj++) {
        const int o = ob + tj * 16 + l16;
        const float bias1 = B1[o];
        const float bias2 = B2[o];
        for (int ti = 0; ti < 4; ti++) {
            const int nl = ti * 16 + quad * 4;                 // D row = quad*4+reg
            for (int r = 0; r < 4; r++)
                D1[(n0 + nl + r) * 256 + o] = __float2bfloat16(acc1[ti][tj][r] + bias1);
            bf16 pv[4];
            for (int r = 0; r < 4; r++)
                pv[r] = __float2bfloat16(acc2[ti][tj][r] + bias2);
            *(uint2*)&D2[o * 4096 + n0 + nl] = *(const uint2*)pv;
        }
    }
}

// ---------------------------------------------------------------------------
// Kernel 2: S = Q.Kt^T (NT, K=256) -> Pt = exp(S) (bf16), L[q] = sum_p exp(S).
// No max-subtraction: correct |S| <= ~10; clamp at 80 is inert insurance.
// ---------------------------------------------------------------------------
__global__ __launch_bounds__(256) void attn_s_kernel(
    const bf16* __restrict__ Qw, const bf16* __restrict__ Ktw,
    bf16* __restrict__ Pt, float* __restrict__ L)
{
    __shared__ __align__(16) bf16 As[128 * 32];
    __shared__ __align__(16) bf16 Bs[128 * 32];
    __shared__ float Lrow[128];

    const int b  = blockIdx.z;
    const int q0 = blockIdx.y * 128;
    const int p0 = blockIdx.x * 128;
    const bf16* A = Qw  + b * (4096 * 256);
    const bf16* B = Ktw + b * (4096 * 256);

    const int tid = threadIdx.x;
    const int wv = tid >> 6, lane = tid & 63, l16 = lane & 15, quad = lane >> 4;
    const int wr = wv >> 1, wc = wv & 1;

    if (tid < 128) Lrow[tid] = 0.0f;

    f32x4 acc[4][4] = {};

    for (int ks = 0; ks < 8; ks++) {
        const int k0 = ks * 32;
        bf16x8 av[2], bv[2];
        for (int c = 0; c < 2; c++) {
            const int ci = c * 256 + tid;
            const int row = ci >> 2, kc = ci & 3;
            av[c] = *(const bf16x8*)&A[(q0 + row) * 256 + k0 + kc * 8];
            bv[c] = *(const bf16x8*)&B[(p0 + row) * 256 + k0 + kc * 8];
        }
        __syncthreads();
        for (int c = 0; c < 2; c++) {
            const int ci = c * 256 + tid;
            *(bf16x8*)&As[ci * 8] = av[c];
            *(bf16x8*)&Bs[ci * 8] = bv[c];
        }
        __syncthreads();
        bf16x8 af[4], bfr[4];
        for (int t = 0; t < 4; t++) {
            af[t]  = *(const bf16x8*)&As[(wr * 64 + t * 16 + l16) * 32 + quad * 8];
            bfr[t] = *(const bf16x8*)&Bs[(wc * 64 + t * 16 + l16) * 32 + quad * 8];
        }
        for (int ti = 0; ti < 4; ti++)
            for (int tj = 0; tj < 4; tj++)
                acc[ti][tj] = __builtin_amdgcn_mfma_f32_16x16x32_bf16(af[ti], bfr[tj], acc[ti][tj], 0, 0, 0);
    }
    __syncthreads();

    bf16* Pdst = Pt + (size_t)b * 4096 * 4096;
    for (int ti = 0; ti < 4; ti++) {
        for (int r = 0; r < 4; r++) {
            const int qrow = wr * 64 + ti * 16 + quad * 4 + r;
            const int q = q0 + qrow;
            float partial = 0.0f;
            for (int tj = 0; tj < 4; tj++) {
                const float e = __expf(fminf(acc[ti][tj][r], 80.0f));
                partial += e;
                const int p = p0 + wc * 64 + tj * 16 + l16;
                Pdst[(size_t)q * 4096 + p] = __float2bfloat16(e);
            }
            atomicAdd(&Lrow[qrow], partial);
        }
    }
    __syncthreads();
    if (tid < 128) atomicAdd(&L[b * 4096 + q0 + tid], Lrow[tid]);
}

// ---------------------------------------------------------------------------
// Kernel 3: O = Vall.Pt^T (NT, K=4096), scale by 1/L[q], store fp32 outputs.
// c' in [0,256) -> img_v, [256,512) -> pc_v (pc_v channel order c*16+d matches
// Vall row order by construction).
// ---------------------------------------------------------------------------
__global__ __launch_bounds__(256) void attn_o_kernel(
    const bf16* __restrict__ Vall, const bf16* __restrict__ Pt,
    const float* __restrict__ L, float* __restrict__ out)
{
    __shared__ __align__(16) bf16 As[128 * 32];
    __shared__ __align__(16) bf16 Bs[128 * 32];

    const int b  = blockIdx.z;
    const int c0 = blockIdx.y * 128;
    const int q0 = blockIdx.x * 128;
    const bf16* A = Vall + (size_t)b * 512 * 4096;
    const bf16* B = Pt   + (size_t)b * 4096 * 4096;

    const int tid = threadIdx.x;
    const int wv = tid >> 6, lane = tid & 63, l16 = lane & 15, quad = lane >> 4;
    const int wr = wv >> 1, wc = wv & 1;

    f32x4 acc[4][4] = {};

    for (int ks = 0; ks < 128; ks++) {
        const int k0 = ks * 32;
        bf16x8 av[2], bv[2];
        for (int c = 0; c < 2; c++) {
            const int ci = c * 256 + tid;
            const int row = ci >> 2, kc = ci & 3;
            av[c] = *(const bf16x8*)&A[(c0 + row) * 4096 + k0 + kc * 8];
            bv[c] = *(const bf16x8*)&B[(q0 + row) * 4096 + k0 + kc * 8];
        }
        __syncthreads();
        for (int c = 0; c < 2; c++) {
            const int ci = c * 256 + tid;
            *(bf16x8*)&As[ci * 8] = av[c];
            *(bf16x8*)&Bs[ci * 8] = bv[c];
        }
        __syncthreads();
        bf16x8 af[4], bfr[4];
        for (int t = 0; t < 4; t++) {
            af[t]  = *(const bf16x8*)&As[(wr * 64 + t * 16 + l16) * 32 + quad * 8];
            bfr[t] = *(const bf16x8*)&Bs[(wc * 64 + t * 16 + l16) * 32 + quad * 8];
        }
        for (int ti = 0; ti < 4; ti++)
            for (int tj = 0; tj < 4; tj++)
                acc[ti][tj] = __builtin_amdgcn_mfma_f32_16x16x32_bf16(af[ti], bfr[tj], acc[ti][tj], 0, 0, 0);
    }

    float rl[4];
    for (int tj = 0; tj < 4; tj++)
        rl[tj] = 1.0f / fmaxf(L[b * 4096 + q0 + wc * 64 + tj * 16 + l16], 1e-10f);

    for (int ti = 0; ti < 4; ti++) {
        for (int r = 0; r < 4; r++) {
            const int c_ = c0 + wr * 64 + ti * 16 + quad * 4 + r;
            const size_t base = (c_ < 256)
                ? ((size_t)b * 1048576 + (size_t)c_ * 4096)
                : (2097152u + (size_t)b * 1048576 + (size_t)(c_ - 256) * 4096);
            for (int tj = 0; tj < 4; tj++) {
                const int q = q0 + wc * 64 + tj * 16 + l16;
                out[base + q] = acc[ti][tj][r] * rl[tj];
            }
        }
    }
}

// ---------------------------------------------------------------------------
// Workspace: [0,4)MB Q | [4,8)MB Kt | [8,16)MB Vall | [16,80)MB Pt | 80MB+ L
// ---------------------------------------------------------------------------
extern "C" void kernel_launch(void* const* d_in, const int* in_sizes, int n_in,
                              void* d_out, int out_size, void* d_ws, size_t ws_size,
                              hipStream_t stream)
{
    const float* img = (const float*)d_in[0];
    const float* pc  = (const float*)d_in[1];
    const float* Wq  = (const float*)d_in[2];
    const float* bq  = (const float*)d_in[3];
    const float* Wk  = (const float*)d_in[4];
    const float* bk  = (const float*)d_in[5];
    const float* Wvi = (const float*)d_in[6];
    const float* bvi = (const float*)d_in[7];
    const float* Wvp = (const float*)d_in[8];
    const float* bvp = (const float*)d_in[9];

    char* ws = (char*)d_ws;
    bf16*  Qw   = (bf16*)(ws);
    bf16*  Ktw  = (bf16*)(ws + (4ull  << 20));
    bf16*  Vall = (bf16*)(ws + (8ull  << 20));
    bf16*  Pt   = (bf16*)(ws + (16ull << 20));
    float* L    = (float*)(ws + (80ull << 20));

    hipMemsetAsync(L, 0, 2 * 4096 * sizeof(float), stream);
    proj_kernel<<<256, 256, 0, stream>>>(img, pc, Wq, bq, Wk, bk,
                                         Wvi, bvi, Wvp, bvp, Qw, Ktw, Vall);
    attn_s_kernel<<<dim3(32, 32, 2), 256, 0, stream>>>(Qw, Ktw, Pt, L);
    attn_o_kernel<<<dim3(32, 4, 2), 256, 0, stream>>>(Vall, Pt, L, (float*)d_out);
}

// Round 4
// 212.041 us; speedup vs baseline: 1.2509x; 1.2509x over previous
//
#include <hip/hip_runtime.h>
#include <hip/hip_bf16.h>

// B=2, IMG_DIM=VOXEL_DIM=QK_DIM=256, H=W=64, N=4096.
// Inputs/outputs FP32; internal GEMMs bf16 MFMA (16x16x32).

typedef __hip_bfloat16 bf16;
typedef __attribute__((ext_vector_type(8))) short bf16x8;   // 8 bf16 = 4 VGPRs
typedef __attribute__((ext_vector_type(4))) float f32x4;

#define AS1 __attribute__((address_space(1)))
#define AS3 __attribute__((address_space(3)))

__device__ __forceinline__ void gld_lds16(const bf16* g, bf16* s) {
    // async global->LDS, 16B/lane; LDS dst = wave-uniform base + lane*16
    __builtin_amdgcn_global_load_lds((const AS1 void*)g, (AS3 void*)s, 16, 0, 0);
}

__device__ __forceinline__ bf16x8 cvt8(const float* __restrict__ p) {
    const float4 a = *(const float4*)p;
    const float4 b = *(const float4*)(p + 4);
    bf16 t[8];
    t[0] = __float2bfloat16(a.x); t[1] = __float2bfloat16(a.y);
    t[2] = __float2bfloat16(a.z); t[3] = __float2bfloat16(a.w);
    t[4] = __float2bfloat16(b.x); t[5] = __float2bfloat16(b.y);
    t[6] = __float2bfloat16(b.z); t[7] = __float2bfloat16(b.w);
    return *(const bf16x8*)t;
}

// ---------------------------------------------------------------------------
// Kernel 1: projections. 512 blocks: blk = s*256 + b*128 + g*64 + ntile.
// Each block: one 64-position x 256-outch GEMM (g=0: Q/Kt; g=1: V).
// XT staged with coalesced float4 gathers (both layouts).
// ---------------------------------------------------------------------------
__global__ __launch_bounds__(256) void proj_kernel(
    const float* __restrict__ img, const float* __restrict__ pc,
    const float* __restrict__ Wq,  const float* __restrict__ bq,
    const float* __restrict__ Wk,  const float* __restrict__ bk,
    const float* __restrict__ Wvi, const float* __restrict__ bvi,
    const float* __restrict__ Wvp, const float* __restrict__ bvp,
    bf16* __restrict__ Qw, bf16* __restrict__ Ktw, bf16* __restrict__ Vall)
{
    __shared__ __align__(16) bf16 XT[64][264];   // [pos][cin], +8 pad

    const int blk = blockIdx.x;
    const int s   = blk >> 8;
    const int b   = (blk >> 7) & 1;
    const int g   = (blk >> 6) & 1;
    const int n0  = (blk & 63) * 64;
    const int tid = threadIdx.x;

    if (s == 0) {
        const float* src = img + b * 1048576;                 // [256][4096]
        for (int k = 0; k < 16; k++) {
            const int i = tid + k * 256;
            const int cin = i >> 4, nl4 = (i & 15) * 4;
            const float4 v = *(const float4*)&src[cin * 4096 + n0 + nl4];
            XT[nl4 + 0][cin] = __float2bfloat16(v.x);
            XT[nl4 + 1][cin] = __float2bfloat16(v.y);
            XT[nl4 + 2][cin] = __float2bfloat16(v.z);
            XT[nl4 + 3][cin] = __float2bfloat16(v.w);
        }
    } else {
        // pc[b][d][h][w][c]: ch = c*16+d, flat = d*65536 + n*16 + c
        const float* src = pc + b * 1048576;
        for (int k = 0; k < 16; k++) {
            const int d = k, u = tid;
            const int nl = u >> 2, c4 = (u & 3) * 4;
            const float4 v = *(const float4*)&src[d * 65536 + (n0 + nl) * 16 + c4];
            XT[nl][(c4 + 0) * 16 + d] = __float2bfloat16(v.x);
            XT[nl][(c4 + 1) * 16 + d] = __float2bfloat16(v.y);
            XT[nl][(c4 + 2) * 16 + d] = __float2bfloat16(v.z);
            XT[nl][(c4 + 3) * 16 + d] = __float2bfloat16(v.w);
        }
    }
    __syncthreads();

    const float* W = s ? (g ? Wvp : Wk) : (g ? Wvi : Wq);
    const float* Bv = s ? (g ? bvp : bk) : (g ? bvi : bq);

    const int wv = tid >> 6, lane = tid & 63, l16 = lane & 15, quad = lane >> 4;
    const int ob = wv * 64;

    f32x4 acc[4][4] = {};

    for (int ks = 0; ks < 8; ks++) {
        const int k0 = ks * 32;
        bf16x8 af[4], wf[4];
        for (int ti = 0; ti < 4; ti++)
            af[ti] = *(const bf16x8*)&XT[ti * 16 + l16][k0 + quad * 8];
        for (int tj = 0; tj < 4; tj++)
            wf[tj] = cvt8(&W[(ob + tj * 16 + l16) * 256 + k0 + quad * 8]);
        for (int ti = 0; ti < 4; ti++)
            for (int tj = 0; tj < 4; tj++)
                acc[ti][tj] = __builtin_amdgcn_mfma_f32_16x16x32_bf16(af[ti], wf[tj], acc[ti][tj], 0, 0, 0);
    }

    if (g == 0) {
        bf16* D1 = (s ? Ktw : Qw) + b * (4096 * 256);          // [n][o]
        for (int tj = 0; tj < 4; tj++) {
            const int o = ob + tj * 16 + l16;
            const float bias = Bv[o];
            for (int ti = 0; ti < 4; ti++) {
                const int nl = ti * 16 + quad * 4;             // D row = quad*4+r
                for (int r = 0; r < 4; r++)
                    D1[(n0 + nl + r) * 256 + o] = __float2bfloat16(acc[ti][tj][r] + bias);
            }
        }
    } else {
        bf16* D2 = Vall + b * (512 * 4096) + (s ? 256 * 4096 : 0);  // [c'][p]
        for (int tj = 0; tj < 4; tj++) {
            const int o = ob + tj * 16 + l16;
            const float bias = Bv[o];
            for (int ti = 0; ti < 4; ti++) {
                const int nl = ti * 16 + quad * 4;
                bf16 pv[4];
                for (int r = 0; r < 4; r++)
                    pv[r] = __float2bfloat16(acc[ti][tj][r] + bias);
                *(uint2*)&D2[o * 4096 + n0 + nl] = *(const uint2*)pv;
            }
        }
    }
}

// ---------------------------------------------------------------------------
// Kernel 2: S = Q.Kt^T (NT, K=256) -> Pt = exp(S) (bf16) + non-atomic
// Lpart[b][q][strip] (strip = 64-wide p range). No max-subtraction (|S|<=~10;
// clamp 80 inert). Shuffle-reduce replaces all atomics.
// ---------------------------------------------------------------------------
__global__ __launch_bounds__(256) void attn_s_kernel(
    const bf16* __restrict__ Qw, const bf16* __restrict__ Ktw,
    bf16* __restrict__ Pt, float* __restrict__ Lpart)
{
    __shared__ __align__(16) bf16 As[128 * 32];
    __shared__ __align__(16) bf16 Bs[128 * 32];

    const int b  = blockIdx.z;
    const int q0 = blockIdx.y * 128;
    const int p0 = blockIdx.x * 128;
    const bf16* A = Qw  + b * (4096 * 256);
    const bf16* B = Ktw + b * (4096 * 256);

    const int tid = threadIdx.x;
    const int wv = tid >> 6, lane = tid & 63, l16 = lane & 15, quad = lane >> 4;
    const int wr = wv >> 1, wc = wv & 1;

    f32x4 acc[4][4] = {};

    for (int ks = 0; ks < 8; ks++) {
        const int k0 = ks * 32;
        bf16x8 av[2], bv[2];
        for (int c = 0; c < 2; c++) {
            const int ci = c * 256 + tid;
            const int row = ci >> 2, kc = ci & 3;
            av[c] = *(const bf16x8*)&A[(q0 + row) * 256 + k0 + kc * 8];
            bv[c] = *(const bf16x8*)&B[(p0 + row) * 256 + k0 + kc * 8];
        }
        __syncthreads();
        for (int c = 0; c < 2; c++) {
            const int ci = c * 256 + tid;
            *(bf16x8*)&As[ci * 8] = av[c];
            *(bf16x8*)&Bs[ci * 8] = bv[c];
        }
        __syncthreads();
        bf16x8 af[4], bfr[4];
        for (int t = 0; t < 4; t++) {
            af[t]  = *(const bf16x8*)&As[(wr * 64 + t * 16 + l16) * 32 + quad * 8];
            bfr[t] = *(const bf16x8*)&Bs[(wc * 64 + t * 16 + l16) * 32 + quad * 8];
        }
        for (int ti = 0; ti < 4; ti++)
            for (int tj = 0; tj < 4; tj++)
                acc[ti][tj] = __builtin_amdgcn_mfma_f32_16x16x32_bf16(af[ti], bfr[tj], acc[ti][tj], 0, 0, 0);
    }

    bf16* Pdst = Pt + (size_t)b * 4096 * 4096;
    const int strip = blockIdx.x * 2 + wc;                    // p strip of 64
    for (int ti = 0; ti < 4; ti++) {
        for (int r = 0; r < 4; r++) {
            const int qrow = wr * 64 + ti * 16 + quad * 4 + r;
            const int q = q0 + qrow;
            float partial = 0.0f;
            for (int tj = 0; tj < 4; tj++) {
                const float e = __expf(fminf(acc[ti][tj][r], 80.0f));
                partial += e;
                Pdst[(size_t)q * 4096 + p0 + wc * 64 + tj * 16 + l16] = __float2bfloat16(e);
            }
            // reduce over the 16 lanes of this quad (same qrow)
            partial += __shfl_xor(partial, 1);
            partial += __shfl_xor(partial, 2);
            partial += __shfl_xor(partial, 4);
            partial += __shfl_xor(partial, 8);
            if (l16 == 0)
                Lpart[(size_t)(b * 4096 + q) * 64 + strip] = partial;
        }
    }
}

// ---------------------------------------------------------------------------
// Kernel 2b: Linv[b][q] = 1 / sum_strip Lpart  (8192 rows)
// ---------------------------------------------------------------------------
__global__ __launch_bounds__(256) void lred_kernel(
    const float* __restrict__ Lpart, float* __restrict__ Linv)
{
    const int row = blockIdx.x * 256 + threadIdx.x;           // [0, 8192)
    const float4* lp = (const float4*)&Lpart[(size_t)row * 64];
    float s = 0.0f;
    for (int i = 0; i < 16; i++) {
        const float4 v = lp[i];
        s += v.x + v.y + v.z + v.w;
    }
    Linv[row] = 1.0f / fmaxf(s, 1e-30f);
}

// ---------------------------------------------------------------------------
// Kernel 3: O = Vall.Pt^T (NT, K=4096) * Linv[q]. Tile 128c x 64q -> 512
// blocks (2/CU). global_load_lds width-16 staging.
// ---------------------------------------------------------------------------
__global__ __launch_bounds__(256) void attn_o_kernel(
    const bf16* __restrict__ Vall, const bf16* __restrict__ Pt,
    const float* __restrict__ Linv, float* __restrict__ out)
{
    __shared__ __align__(16) bf16 As[128 * 32];   // c-rows
    __shared__ __align__(16) bf16 Bs[64 * 32];    // q-rows

    const int b  = blockIdx.z;
    const int c0 = blockIdx.y * 128;
    const int q0 = blockIdx.x * 64;
    const bf16* A = Vall + (size_t)b * 512 * 4096;
    const bf16* B = Pt   + (size_t)b * 4096 * 4096;

    const int tid = threadIdx.x;
    const int wv = tid >> 6, lane = tid & 63, l16 = lane & 15, quad = lane >> 4;
    const int wr = wv >> 1, wc = wv & 1;          // wave: 64c x 32q quadrant

    f32x4 acc[4][2] = {};

    const int arow = tid >> 2, akc = tid & 3;     // A: 2 rounds of 256 chunks
    for (int ks = 0; ks < 128; ks++) {
        const int k0 = ks * 32;
        gld_lds16(A + (c0 + arow) * 4096 + k0 + akc * 8, As + tid * 8);
        gld_lds16(A + (c0 + 64 + arow) * 4096 + k0 + akc * 8, As + 2048 + tid * 8);
        gld_lds16(B + (q0 + arow) * 4096 + k0 + akc * 8, Bs + tid * 8);
        __syncthreads();
        bf16x8 af[4], bfr[2];
        for (int t = 0; t < 4; t++)
            af[t]  = *(const bf16x8*)&As[(wr * 64 + t * 16 + l16) * 32 + quad * 8];
        for (int t = 0; t < 2; t++)
            bfr[t] = *(const bf16x8*)&Bs[(wc * 32 + t * 16 + l16) * 32 + quad * 8];
        for (int ti = 0; ti < 4; ti++)
            for (int tj = 0; tj < 2; tj++)
                acc[ti][tj] = __builtin_amdgcn_mfma_f32_16x16x32_bf16(af[ti], bfr[tj], acc[ti][tj], 0, 0, 0);
        __syncthreads();
    }

    float rl[2];
    for (int tj = 0; tj < 2; tj++)
        rl[tj] = Linv[b * 4096 + q0 + wc * 32 + tj * 16 + l16];

    for (int ti = 0; ti < 4; ti++) {
        for (int r = 0; r < 4; r++) {
            const int c_ = c0 + wr * 64 + ti * 16 + quad * 4 + r;
            const size_t base = (c_ < 256)
                ? ((size_t)b * 1048576 + (size_t)c_ * 4096)
                : (2097152u + (size_t)b * 1048576 + (size_t)(c_ - 256) * 4096);
            for (int tj = 0; tj < 2; tj++) {
                const int q = q0 + wc * 32 + tj * 16 + l16;
                out[base + q] = acc[ti][tj][r] * rl[tj];
            }
        }
    }
}

// ---------------------------------------------------------------------------
// ws: [0,4)MB Q | [4,8)MB Kt | [8,16)MB Vall | [16,80)MB Pt |
//     [80,82)MB Lpart fp32 [2][4096][64] | [82MB,+32KB) Linv fp32 [2][4096]
// ---------------------------------------------------------------------------
extern "C" void kernel_launch(void* const* d_in, const int* in_sizes, int n_in,
                              void* d_out, int out_size, void* d_ws, size_t ws_size,
                              hipStream_t stream)
{
    const float* img = (const float*)d_in[0];
    const float* pc  = (const float*)d_in[1];
    const float* Wq  = (const float*)d_in[2];
    const float* bq  = (const float*)d_in[3];
    const float* Wk  = (const float*)d_in[4];
    const float* bk  = (const float*)d_in[5];
    const float* Wvi = (const float*)d_in[6];
    const float* bvi = (const float*)d_in[7];
    const float* Wvp = (const float*)d_in[8];
    const float* bvp = (const float*)d_in[9];

    char* ws = (char*)d_ws;
    bf16*  Qw    = (bf16*)(ws);
    bf16*  Ktw   = (bf16*)(ws + (4ull  << 20));
    bf16*  Vall  = (bf16*)(ws + (8ull  << 20));
    bf16*  Pt    = (bf16*)(ws + (16ull << 20));
    float* Lpart = (float*)(ws + (80ull << 20));
    float* Linv  = (float*)(ws + (82ull << 20));

    proj_kernel<<<512, 256, 0, stream>>>(img, pc, Wq, bq, Wk, bk,
                                         Wvi, bvi, Wvp, bvp, Qw, Ktw, Vall);
    attn_s_kernel<<<dim3(32, 32, 2), 256, 0, stream>>>(Qw, Ktw, Pt, Lpart);
    lred_kernel<<<32, 256, 0, stream>>>(Lpart, Linv);
    attn_o_kernel<<<dim3(64, 4, 2), 256, 0, stream>>>(Vall, Pt, Linv, (float*)d_out);
}